// Round 1
// baseline (407.701 us; speedup 1.0000x reference)
//
#include <hip/hip_runtime.h>
#include <hip/hip_bf16.h>
#include <math.h>

typedef __attribute__((ext_vector_type(4))) float f32x4;
typedef __attribute__((ext_vector_type(8))) short short8;
typedef unsigned short ushort_t;
typedef unsigned int uint_t;

__device__ __forceinline__ float b2f(unsigned short u) {
    unsigned int v = ((unsigned int)u) << 16;
    return __uint_as_float(v);
}
__device__ __forceinline__ unsigned short f2b(float f) {
    unsigned int x = __float_as_uint(f);
    unsigned int r = (x + 0x7fffu + ((x >> 16) & 1u)) >> 16;
    return (unsigned short)r;
}

// ---------------------------------------------------------------- small prep
__global__ void zero_kernel(int* p, int n) {
    int i = blockIdx.x * 256 + threadIdx.x;
    if (i < n) p[i] = 0;
}

// WbT[n][k] (bf16, [256,128]) = B^T of [W1|W2] so PQ = h @ [W1|W2]
__global__ void pack_wb(const float* __restrict__ W_pre, ushort_t* __restrict__ WbT) {
    int i = blockIdx.x * 256 + threadIdx.x;
    if (i >= 256 * 128) return;
    int nn = i >> 7, k = i & 127;
    float v = (nn < 128) ? W_pre[k * 128 + nn] : W_pre[(128 + k) * 128 + (nn - 128)];
    WbT[i] = f2b(v);
}

// WcT[n][k] (bf16, [384,896]): block matrix [[Wp0,0,0],[Wp1,Wp2,Wp3]] transposed
__global__ void pack_wc(const float* __restrict__ W_post, ushort_t* __restrict__ WcT) {
    int i = blockIdx.x * 256 + threadIdx.x;
    if (i >= 384 * 896) return;
    int nn = i / 896, k = i % 896;
    float v;
    if (k < 128) {
        v = (nn < 128) ? W_post[k * 128 + nn] : 0.f;
    } else {
        int ka = k - 128;
        if (nn < 128)      v = W_post[(128 + ka) * 128 + nn];
        else if (nn < 256) v = W_post[(896 + ka) * 128 + (nn - 128)];
        else               v = W_post[(1664 + ka) * 128 + (nn - 256)];
    }
    WcT[i] = f2b(v);
}

// X[:,0:128] = bf16(h)   (X row stride 896)
__global__ void conv_h(const float* __restrict__ h, ushort_t* __restrict__ X, int Nn) {
    int g = blockIdx.x * 256 + threadIdx.x;
    if (g >= Nn * 32) return;
    int n = g >> 5, c4 = (g & 31) * 4;
    float4 hv = *(const float4*)&h[(size_t)n * 128 + c4];
    ushort4 o;
    o.x = f2b(hv.x); o.y = f2b(hv.y); o.z = f2b(hv.z); o.w = f2b(hv.w);
    *(ushort4*)&X[(size_t)n * 896 + c4] = o;
}

// ---------------------------------------------------------------- CSR build
__global__ void hist_kernel(const int* __restrict__ dst, int* __restrict__ counts, int E) {
    int i = blockIdx.x * 256 + threadIdx.x;
    if (i < E) atomicAdd(&counts[dst[i]], 1);
}

// single block exclusive scan over counts[0..Nn-1] -> offsets (in place) + cursors
__global__ __launch_bounds__(1024) void scan_kernel(int* __restrict__ counts,
                                                    int* __restrict__ cursors, int Nn) {
    __shared__ int part[1024];
    int t = threadIdx.x;
    int base = t * 40;
    int loc[40];
    int s = 0;
#pragma unroll
    for (int i = 0; i < 40; ++i) {
        int idx = base + i;
        int v = (idx < Nn) ? counts[idx] : 0;
        loc[i] = s; s += v;
    }
    part[t] = s;
    __syncthreads();
    for (int off = 1; off < 1024; off <<= 1) {
        int v = part[t];
        int u = (t >= off) ? part[t - off] : 0;
        __syncthreads();
        part[t] = v + u;
        __syncthreads();
    }
    int pre = (t > 0) ? part[t - 1] : 0;
#pragma unroll
    for (int i = 0; i < 40; ++i) {
        int idx = base + i;
        if (idx < Nn) { int o = pre + loc[i]; counts[idx] = o; cursors[idx] = o; }
    }
    if (t == 1023) counts[Nn] = part[1023];
}

__global__ void scatter_kernel(const int* __restrict__ dst, int* __restrict__ cursors,
                               int* __restrict__ perm, int E) {
    int i = blockIdx.x * 256 + threadIdx.x;
    if (i < E) {
        int v = dst[i];
        int p = atomicAdd(&cursors[v], 1);
        perm[p] = i;
    }
}

// ---------------------------------------------------------------- bf16 MFMA GEMM (B^T)
// C[M,N] = A[M,K](bf16,lda) @ Bt[N,K]^T(bf16,ldb=K).  128x128 tile, BK=64, 4 waves.
template <int OUT_BF16>
__global__ __launch_bounds__(256) void gemm_bt(const ushort_t* __restrict__ A, int lda,
                                               const ushort_t* __restrict__ Bt, int ldb,
                                               void* __restrict__ Cv, int ldc,
                                               int M, int K) {
    __shared__ ushort_t ldsbuf[2 * 128 * 64];
    const int tid = threadIdx.x, wid = tid >> 6, lane = tid & 63;
    const int m0 = blockIdx.x * 128, n0 = blockIdx.y * 128;
    f32x4 acc[4][4] = {};
    const int wrow = (wid >> 1) * 64, wcol = (wid & 1) * 64;

    for (int kt = 0; kt < K; kt += 64) {
#pragma unroll
        for (int rnd = 0; rnd < 4; ++rnd) {
            int libase = rnd * 256 + wid * 64;
            {   // A tile: chunk li = r*8 + (c ^ (r&7)), 16B chunks
                int lc = libase + lane;
                int r = lc >> 3, cs = lc & 7;
                int c = cs ^ (r & 7);
                int row = m0 + r; row = row < M ? row : M - 1;
                const ushort_t* g = A + (size_t)row * lda + (kt + c * 8);
                __builtin_amdgcn_global_load_lds(
                    (const __attribute__((address_space(1))) unsigned int*)g,
                    (__attribute__((address_space(3))) unsigned int*)&ldsbuf[(size_t)libase * 8],
                    16, 0, 0);
            }
            {   // B tile (rows of Bt)
                int lc = libase + lane;
                int r = lc >> 3, cs = lc & 7;
                int c = cs ^ (r & 7);
                const ushort_t* g = Bt + (size_t)(n0 + r) * ldb + (kt + c * 8);
                __builtin_amdgcn_global_load_lds(
                    (const __attribute__((address_space(1))) unsigned int*)g,
                    (__attribute__((address_space(3))) unsigned int*)&ldsbuf[8192 + (size_t)libase * 8],
                    16, 0, 0);
            }
        }
        __syncthreads();
#pragma unroll
        for (int kk = 0; kk < 2; ++kk) {
            short8 af[4], bfr[4];
#pragma unroll
            for (int f = 0; f < 4; ++f) {
                int r = wrow + f * 16 + (lane & 15);
                int c16 = kk * 4 + (lane >> 4);
                int ch = r * 8 + (c16 ^ (r & 7));
                af[f] = *(const short8*)&ldsbuf[ch * 8];
            }
#pragma unroll
            for (int f = 0; f < 4; ++f) {
                int r = wcol + f * 16 + (lane & 15);
                int c16 = kk * 4 + (lane >> 4);
                int ch = r * 8 + (c16 ^ (r & 7));
                bfr[f] = *(const short8*)&ldsbuf[8192 + ch * 8];
            }
#pragma unroll
            for (int i = 0; i < 4; ++i)
#pragma unroll
                for (int j = 0; j < 4; ++j)
                    acc[i][j] = __builtin_amdgcn_mfma_f32_16x16x32_bf16(af[i], bfr[j], acc[i][j], 0, 0, 0);
        }
        __syncthreads();
    }
#pragma unroll
    for (int i = 0; i < 4; ++i)
#pragma unroll
        for (int j = 0; j < 4; ++j)
#pragma unroll
            for (int q = 0; q < 4; ++q) {
                int row = m0 + wrow + i * 16 + (lane >> 4) * 4 + q;
                int col = n0 + wcol + j * 16 + (lane & 15);
                if (row < M) {
                    if (OUT_BF16) ((ushort_t*)Cv)[(size_t)row * ldc + col] = f2b(acc[i][j][q]);
                    else          ((float*)Cv)[(size_t)row * ldc + col] = acc[i][j][q];
                }
            }
}

// ---------------------------------------------------------------- aggregation
// one wave per node; m_e = P[src] + Q[n] + e@W3 + b_pre computed on the fly
__global__ __launch_bounds__(256) void agg_kernel(
    const ushort_t* __restrict__ PQ, ushort_t* __restrict__ X,
    const float* __restrict__ ef, const float* __restrict__ eig,
    const int* __restrict__ src, const int* __restrict__ perm,
    const int* __restrict__ offs, const float* __restrict__ h,
    const float* __restrict__ W_pre, const float* __restrict__ b_pre,
    float* __restrict__ scal, int Nn) {
    __shared__ float W3s[16][128];
    __shared__ float bps[128];
    int tid = threadIdx.x;
    for (int i = tid; i < 2048; i += 256) {
        int j = i >> 7, c = i & 127;
        W3s[j][c] = W_pre[(256 + j) * 128 + c];
    }
    if (tid < 128) bps[tid] = b_pre[tid];
    __syncthreads();
    int wid = tid >> 6, lane = tid & 63;
    int n = blockIdx.x * 4 + wid;
    if (n >= Nn) return;
    int off0 = offs[n], off1 = offs[n + 1];
    int deg = off1 - off0;
    int d0 = lane * 2;

    uint_t qw = *(const uint_t*)&PQ[(size_t)n * 256 + 128 + d0];
    float q0 = b2f((ushort_t)(qw & 0xffff)), q1 = b2f((ushort_t)(qw >> 16));
    float bp0 = bps[d0], bp1 = bps[d0 + 1];
    float eigd = eig[n * 2 + 1];

    float s0 = 0, s1 = 0, ss0 = 0, ss1 = 0, av0 = 0, av1 = 0, dv0 = 0, dv1 = 0, den = 0;
    float mx0 = -1e30f, mx1 = -1e30f, mn0 = 1e30f, mn1 = 1e30f;

    for (int i = off0; i < off1; ++i) {
        int eid = perm[i];
        int sv = src[eid];
        float ddv = eig[sv * 2 + 1] - eigd;
        uint_t pw = *(const uint_t*)&PQ[(size_t)sv * 256 + d0];
        const float4* ep = (const float4*)(ef + (size_t)eid * 16);
        float4 ea = ep[0], eb = ep[1], ec = ep[2], ed = ep[3];
        float ev[16] = {ea.x, ea.y, ea.z, ea.w, eb.x, eb.y, eb.z, eb.w,
                        ec.x, ec.y, ec.z, ec.w, ed.x, ed.y, ed.z, ed.w};
        float r0 = 0.f, r1 = 0.f;
#pragma unroll
        for (int j = 0; j < 16; ++j) {
            float2 w = *(const float2*)&W3s[j][d0];
            r0 = fmaf(ev[j], w.x, r0);
            r1 = fmaf(ev[j], w.y, r1);
        }
        float m0v = b2f((ushort_t)(pw & 0xffff)) + q0 + r0 + bp0;
        float m1v = b2f((ushort_t)(pw >> 16)) + q1 + r1 + bp1;
        float ad = fabsf(ddv);
        s0 += m0v; s1 += m1v;
        ss0 = fmaf(m0v, m0v, ss0); ss1 = fmaf(m1v, m1v, ss1);
        mx0 = fmaxf(mx0, m0v); mx1 = fmaxf(mx1, m1v);
        mn0 = fminf(mn0, m0v); mn1 = fminf(mn1, m1v);
        av0 = fmaf(m0v, ad, av0); av1 = fmaf(m1v, ad, av1);
        dv0 = fmaf(m0v, ddv, dv0); dv1 = fmaf(m1v, ddv, dv1);
        den += ad;
    }

    size_t xb = (size_t)n * 896 + 128;
    float2 hv = *(const float2*)&h[(size_t)n * 128 + d0];
    float o[12];
    if (deg > 0) {
        float inv = 1.f / (float)deg;
        float mean0 = s0 * inv, mean1 = s1 * inv;
        float var0 = fmaxf(ss0 * inv - mean0 * mean0, 0.f);
        float var1 = fmaxf(ss1 * inv - mean1 * mean1, 0.f);
        float sd0 = sqrtf(var0 + 1e-5f), sd1 = sqrtf(var1 + 1e-5f);
        float idn = 1.f / (den + 1e-8f);
        o[0] = mean0; o[1] = mean1; o[2] = mx0; o[3] = mx1; o[4] = mn0; o[5] = mn1;
        o[6] = sd0; o[7] = sd1; o[8] = av0 * idn; o[9] = av1 * idn;
        o[10] = dv0 * idn - hv.x; o[11] = dv1 * idn - hv.y;
    } else {
#pragma unroll
        for (int k = 0; k < 12; ++k) o[k] = 0.f;
    }
#pragma unroll
    for (int a = 0; a < 6; ++a) {
        uint_t w = (uint_t)f2b(o[2 * a]) | ((uint_t)f2b(o[2 * a + 1]) << 16);
        *(uint_t*)&X[xb + a * 128 + d0] = w;
    }
    if (lane == 0) {
        float degc = deg > 0 ? (float)deg : 1.f;
        float logd = logf(degc + 1.f);
        scal[n * 2] = logd * (1.f / 2.772588722239781f);
        scal[n * 2 + 1] = 2.772588722239781f / logd;
    }
}

// ---------------------------------------------------------------- epilogue
__global__ __launch_bounds__(256) void epilogue_kernel(
    const float* __restrict__ O3, const float* __restrict__ h,
    const float* __restrict__ snorm, const float* __restrict__ scal,
    const float* __restrict__ b_post, float* __restrict__ out, int Nn) {
    int g = blockIdx.x * 256 + threadIdx.x;
    if (g >= Nn * 32) return;
    int n = g >> 5, c4 = (g & 31) * 4;
    float a = scal[n * 2], b = scal[n * 2 + 1], sn = snorm[n];
    const float* base = O3 + (size_t)n * 384 + c4;
    float4 o1 = *(const float4*)base;
    float4 o2 = *(const float4*)(base + 128);
    float4 o3 = *(const float4*)(base + 256);
    float4 bp = *(const float4*)&b_post[c4];
    float4 hv = *(const float4*)&h[(size_t)n * 128 + c4];
    float4 r;
    r.x = fmaxf((o1.x + a * o2.x + b * o3.x + bp.x) * sn, 0.f) + hv.x;
    r.y = fmaxf((o1.y + a * o2.y + b * o3.y + bp.y) * sn, 0.f) + hv.y;
    r.z = fmaxf((o1.z + a * o2.z + b * o3.z + bp.z) * sn, 0.f) + hv.z;
    r.w = fmaxf((o1.w + a * o2.w + b * o3.w + bp.w) * sn, 0.f) + hv.w;
    *(float4*)&out[(size_t)n * 128 + c4] = r;
}

// ---------------------------------------------------------------- launch
extern "C" void kernel_launch(void* const* d_in, const int* in_sizes, int n_in,
                              void* d_out, int out_size, void* d_ws, size_t ws_size,
                              hipStream_t stream) {
    const float* h      = (const float*)d_in[0];
    const float* ef     = (const float*)d_in[1];
    const float* eig    = (const float*)d_in[2];
    const float* snorm  = (const float*)d_in[3];
    const int*   src    = (const int*)d_in[4];
    const int*   dst    = (const int*)d_in[5];
    const float* W_pre  = (const float*)d_in[6];
    const float* b_pre  = (const float*)d_in[7];
    const float* W_post = (const float*)d_in[8];
    const float* b_post = (const float*)d_in[9];
    int Nn = in_sizes[0] / 128;
    int E  = in_sizes[4];
    float* out = (float*)d_out;

    char* ws = (char*)d_ws;
    size_t off = 0;
    auto alloc = [&](size_t bytes) {
        size_t o = off;
        off = (off + bytes + 255) & ~(size_t)255;
        return o;
    };
    size_t o_counts  = alloc(((size_t)Nn + 1) * 4);
    size_t o_cursors = alloc((size_t)Nn * 4);
    size_t o_perm    = alloc((size_t)E * 4);
    size_t o_PQ      = alloc((size_t)Nn * 256 * 2);
    size_t o_X       = alloc((size_t)Nn * 896 * 2);
    size_t o_O3      = alloc((size_t)Nn * 384 * 4);
    size_t o_scal    = alloc((size_t)Nn * 2 * 4);
    size_t o_wb      = alloc(256 * 128 * 2);
    size_t o_wc      = alloc(384 * 896 * 2);
    (void)ws_size;

    int*      counts  = (int*)(ws + o_counts);
    int*      cursors = (int*)(ws + o_cursors);
    int*      perm    = (int*)(ws + o_perm);
    ushort_t* PQ      = (ushort_t*)(ws + o_PQ);
    ushort_t* X       = (ushort_t*)(ws + o_X);
    float*    O3      = (float*)(ws + o_O3);
    float*    scal    = (float*)(ws + o_scal);
    ushort_t* WbT     = (ushort_t*)(ws + o_wb);
    ushort_t* WcT     = (ushort_t*)(ws + o_wc);

    zero_kernel<<<(Nn + 1 + 255) / 256, 256, 0, stream>>>(counts, Nn + 1);
    pack_wb<<<(256 * 128 + 255) / 256, 256, 0, stream>>>(W_pre, WbT);
    pack_wc<<<(384 * 896 + 255) / 256, 256, 0, stream>>>(W_post, WcT);
    conv_h<<<(Nn * 32 + 255) / 256, 256, 0, stream>>>(h, X, Nn);
    hist_kernel<<<(E + 255) / 256, 256, 0, stream>>>(dst, counts, E);
    scan_kernel<<<1, 1024, 0, stream>>>(counts, cursors, Nn);
    scatter_kernel<<<(E + 255) / 256, 256, 0, stream>>>(dst, cursors, perm, E);

    dim3 gpq((Nn + 127) / 128, 2);
    gemm_bt<1><<<gpq, 256, 0, stream>>>(X, 896, WbT, 128, (void*)PQ, 256, Nn, 128);

    agg_kernel<<<(Nn + 3) / 4, 256, 0, stream>>>(PQ, X, ef, eig, src, perm, counts, h,
                                                 W_pre, b_pre, scal, Nn);

    dim3 gpo((Nn + 127) / 128, 3);
    gemm_bt<0><<<gpo, 256, 0, stream>>>(X, 896, WcT, 896, (void*)O3, 384, Nn, 896);

    epilogue_kernel<<<(Nn * 32 + 255) / 256, 256, 0, stream>>>(O3, h, snorm, scal, b_post,
                                                               out, Nn);
}